// Round 1
// baseline (113.553 us; speedup 1.0000x reference)
//
#include <hip/hip_runtime.h>
#include <math.h>

#define NB 131072
#define NM 32
#define EC 2.7182818284590452f
#define TS 0.17677669529663687f   // 1/sqrt(32)
#define L2E 1.4426950408889634f
#define LN2F 0.6931471805599453f

// ws layout (floats):
//   [0, 1024)        : Gsym (symmetrized Gamma, row-major)
//   [1024, 1056)     : mode_min[c] - EC   (pre-subtracted)
//   [2048, 2048+8192): per-block partial column mins (256 blocks x 32 cols)

#if __has_builtin(__builtin_amdgcn_exp2f)
__device__ __forceinline__ float fexp2(float x) { return __builtin_amdgcn_exp2f(x); }
#else
__device__ __forceinline__ float fexp2(float x) { return exp2f(x); }
#endif
#if __has_builtin(__builtin_amdgcn_logf)
__device__ __forceinline__ float flog2(float x) { return __builtin_amdgcn_logf(x); }
#else
__device__ __forceinline__ float flog2(float x) { return __log2f(x); }
#endif
#if __has_builtin(__builtin_amdgcn_rcpf)
__device__ __forceinline__ float frcp(float x) { return __builtin_amdgcn_rcpf(x); }
#else
__device__ __forceinline__ float frcp(float x) { return 1.0f / x; }
#endif

// ---------------- Kernel A: per-block partial column minima ----------------
__global__ __launch_bounds__(256) void k_min(const float* __restrict__ phi,
                                             float* __restrict__ ws) {
    __shared__ float sm[1024];
    const int tid = threadIdx.x;
    const int g = blockIdx.x * 256 + tid;
    const float4* __restrict__ p4 = (const float4*)phi;
    float4 m = p4[g];
    #pragma unroll
    for (int k = 1; k < 16; ++k) {
        float4 v = p4[g + k * 65536];
        m.x = fminf(m.x, v.x); m.y = fminf(m.y, v.y);
        m.z = fminf(m.z, v.z); m.w = fminf(m.w, v.w);
    }
    sm[tid * 4 + 0] = m.x; sm[tid * 4 + 1] = m.y;
    sm[tid * 4 + 2] = m.z; sm[tid * 4 + 3] = m.w;
    __syncthreads();
    #pragma unroll
    for (int s = 128; s >= 8; s >>= 1) {
        if (tid < s) {
            sm[tid * 4 + 0] = fminf(sm[tid * 4 + 0], sm[(tid + s) * 4 + 0]);
            sm[tid * 4 + 1] = fminf(sm[tid * 4 + 1], sm[(tid + s) * 4 + 1]);
            sm[tid * 4 + 2] = fminf(sm[tid * 4 + 2], sm[(tid + s) * 4 + 2]);
            sm[tid * 4 + 3] = fminf(sm[tid * 4 + 3], sm[(tid + s) * 4 + 3]);
        }
        __syncthreads();
    }
    if (tid < 8) {
        #pragma unroll
        for (int s2 = 0; s2 < 4; ++s2)
            ws[2048 + blockIdx.x * 32 + tid * 4 + s2] = sm[tid * 4 + s2];
    }
}

// ------- Kernel B: final min reduce + Gamma symmetrization into ws --------
__global__ __launch_bounds__(256) void k_prep(const float* __restrict__ Gamma,
                                              float* __restrict__ ws) {
    __shared__ float sm[256];
    const int tid = threadIdx.x;
    const int c = tid & 31, h = tid >> 5;      // 8 groups of 32 partial-blocks
    float m = INFINITY;
    #pragma unroll
    for (int b = 0; b < 32; ++b)
        m = fminf(m, ws[2048 + (h * 32 + b) * 32 + c]);
    sm[tid] = m;
    __syncthreads();
    if (tid < 32) {
        float mm = sm[tid];
        #pragma unroll
        for (int g2 = 1; g2 < 8; ++g2) mm = fminf(mm, sm[g2 * 32 + tid]);
        ws[1024 + tid] = mm - EC;
    }
    // Gsym[i][j] = Gamma[min(i,j), max(i,j)]
    #pragma unroll
    for (int k = 0; k < 4; ++k) {
        int idx = tid + 256 * k;
        int i = idx >> 5, j = idx & 31;
        int lo = min(i, j), hi = i + j - lo;
        ws[idx] = Gamma[lo * 32 + hi];
    }
}

// ---------------- Kernel C: main (row-per-thread) --------------------------
// 512 blocks x 256 threads, one row per thread. L[32] stays in REGISTERS
// (all j-indexing static). Dynamically-indexed values (L_i at iteration i,
// and x_i) go through the 32 KB same-thread LDS mirror (conflict-free,
// 2 lanes/bank). i-loop unrolled x4 (NOT fully): the LDS mirror means no
// register array is ever dynamically indexed, so scratch demotion (R2 bug)
// cannot trigger; unroll-4 batches 4 ds_reads of Li + 4 g-row s_load bursts
// per exposed-latency window (was 1 each, 32 windows -> 8) and gives 16
// independent exp2/acc chains. __launch_bounds__(256,2) pins VGPR<=256 so
// occupancy stays at 2 waves/SIMD.
__global__ __launch_bounds__(256, 2) void k_main(const float* __restrict__ phi,
                                                 const float* __restrict__ w,
                                                 const float* __restrict__ ws,
                                                 float* __restrict__ out) {
    __shared__ float sL[32 * 256];
    const int tid = threadIdx.x;
    const size_t row = (size_t)blockIdx.x * 256 + tid;
    const float* __restrict__ pr = phi + row * NM;
    const float* __restrict__ mme = ws + 1024;   // mode_min - e (uniform)

    float L[32];
    #pragma unroll
    for (int k = 0; k < 8; ++k) {
        float4 v = ((const float4*)pr)[k];
        // phic = max(phi - mode_min + e, e) = max(phi - (mode_min - e), e)
        float a0 = fmaxf(v.x - mme[4 * k + 0], EC);
        float a1 = fmaxf(v.y - mme[4 * k + 1], EC);
        float a2 = fmaxf(v.z - mme[4 * k + 2], EC);
        float a3 = fmaxf(v.w - mme[4 * k + 3], EC);
        L[4 * k + 0] = flog2(a0); L[4 * k + 1] = flog2(a1);
        L[4 * k + 2] = flog2(a2); L[4 * k + 3] = flog2(a3);
    }
    #pragma unroll
    for (int j = 0; j < 32; ++j) sL[j * 256 + tid] = L[j];
    // no __syncthreads: sL slots are strictly same-thread

    #pragma unroll 1
    for (int it = 0; it < 32; it += 4) {
        // batch the 4 dynamic Li reads (independent ds_reads, one wait)
        const float Li0 = sL[(it + 0) * 256 + tid];
        const float Li1 = sL[(it + 1) * 256 + tid];
        const float Li2 = sL[(it + 2) * 256 + tid];
        const float Li3 = sL[(it + 3) * 256 + tid];
        const float w0 = w[it + 0], w1 = w[it + 1];
        const float w2 = w[it + 2], w3 = w[it + 3];
        const float* __restrict__ g0 = ws + (it + 0) * 32;  // uniform s_loads
        const float* __restrict__ g1 = ws + (it + 1) * 32;
        const float* __restrict__ g2 = ws + (it + 2) * 32;
        const float* __restrict__ g3 = ws + (it + 3) * 32;
        float a00 = 0.f, a01 = 0.f, a02 = 0.f, a03 = 0.f;
        float a10 = 0.f, a11 = 0.f, a12 = 0.f, a13 = 0.f;
        float a20 = 0.f, a21 = 0.f, a22 = 0.f, a23 = 0.f;
        float a30 = 0.f, a31 = 0.f, a32 = 0.f, a33 = 0.f;
        #pragma unroll
        for (int j = 0; j < 32; j += 4) {
            const float lj0 = L[j + 0], lj1 = L[j + 1];
            const float lj2 = L[j + 2], lj3 = L[j + 3];
            // phic_i^g * phic_j^(1-g) = 2^(L_j + g*(L_i - L_j))
            a00 += fexp2(fmaf(g0[j + 0], Li0 - lj0, lj0));
            a01 += fexp2(fmaf(g0[j + 1], Li0 - lj1, lj1));
            a02 += fexp2(fmaf(g0[j + 2], Li0 - lj2, lj2));
            a03 += fexp2(fmaf(g0[j + 3], Li0 - lj3, lj3));
            a10 += fexp2(fmaf(g1[j + 0], Li1 - lj0, lj0));
            a11 += fexp2(fmaf(g1[j + 1], Li1 - lj1, lj1));
            a12 += fexp2(fmaf(g1[j + 2], Li1 - lj2, lj2));
            a13 += fexp2(fmaf(g1[j + 3], Li1 - lj3, lj3));
            a20 += fexp2(fmaf(g2[j + 0], Li2 - lj0, lj0));
            a21 += fexp2(fmaf(g2[j + 1], Li2 - lj1, lj1));
            a22 += fexp2(fmaf(g2[j + 2], Li2 - lj2, lj2));
            a23 += fexp2(fmaf(g2[j + 3], Li2 - lj3, lj3));
            a30 += fexp2(fmaf(g3[j + 0], Li3 - lj0, lj0));
            a31 += fexp2(fmaf(g3[j + 1], Li3 - lj1, lj1));
            a32 += fexp2(fmaf(g3[j + 2], Li3 - lj2, lj2));
            a33 += fexp2(fmaf(g3[j + 3], Li3 - lj3, lj3));
        }
        // fullsum's diagonal term == phic_i = 2^Li, so
        // off-sum + (1+w)*phic = fullsum + w*phic
        sL[(it + 0) * 256 + tid] =
            -TS * ((((a00 + a01) + (a02 + a03))) + w0 * fexp2(Li0));
        sL[(it + 1) * 256 + tid] =
            -TS * ((((a10 + a11) + (a12 + a13))) + w1 * fexp2(Li1));
        sL[(it + 2) * 256 + tid] =
            -TS * ((((a20 + a21) + (a22 + a23))) + w2 * fexp2(Li2));
        sL[(it + 3) * 256 + tid] =
            -TS * ((((a30 + a31) + (a32 + a33))) + w3 * fexp2(Li3));
    }

    float xs[32];
    #pragma unroll
    for (int i = 0; i < 32; ++i) xs[i] = sL[i * 256 + tid];
    float m = xs[0];
    #pragma unroll
    for (int i = 1; i < 32; ++i) m = fmaxf(m, xs[i]);
    float p[32];
    float s = 0.f;
    #pragma unroll
    for (int i = 0; i < 32; ++i) { p[i] = fexp2((xs[i] - m) * L2E); s += p[i]; }
    const float inv = frcp(s);
    const float lns = flog2(s) * LN2F;   // ln(s)

    float* __restrict__ oa = out + row * NM;
    float* __restrict__ ol = out + (size_t)NB * NM + row * NM;
    #pragma unroll
    for (int k = 0; k < 8; ++k) {
        float4 a4 = { p[4 * k + 0] * inv, p[4 * k + 1] * inv,
                      p[4 * k + 2] * inv, p[4 * k + 3] * inv };
        float4 l4 = { (xs[4 * k + 0] - m) - lns, (xs[4 * k + 1] - m) - lns,
                      (xs[4 * k + 2] - m) - lns, (xs[4 * k + 3] - m) - lns };
        ((float4*)oa)[k] = a4;
        ((float4*)ol)[k] = l4;
    }
}

extern "C" void kernel_launch(void* const* d_in, const int* in_sizes, int n_in,
                              void* d_out, int out_size, void* d_ws, size_t ws_size,
                              hipStream_t stream) {
    (void)in_sizes; (void)n_in; (void)out_size; (void)ws_size;
    const float* phi   = (const float*)d_in[0];
    const float* Gamma = (const float*)d_in[1];
    const float* w     = (const float*)d_in[2];
    float* out = (float*)d_out;
    float* wsf = (float*)d_ws;

    k_min<<<256, 256, 0, stream>>>(phi, wsf);
    k_prep<<<1, 256, 0, stream>>>(Gamma, wsf);
    k_main<<<512, 256, 0, stream>>>(phi, w, wsf, out);
}

// Round 2
// 105.192 us; speedup vs baseline: 1.0795x; 1.0795x over previous
//
#include <hip/hip_runtime.h>
#include <math.h>

#define NB 131072
#define NM 32
#define EC 2.7182818284590452f
#define TS 0.17677669529663687f   // 1/sqrt(32)
#define L2E 1.4426950408889634f
#define LN2F 0.6931471805599453f

// ws layout (floats):
//   [0, 1024)        : Gsym (symmetrized Gamma, row-major)
//   [1024, 1056)     : mode_min[c] - EC   (pre-subtracted)
//   [2048, 2048+8192): per-block partial column mins (256 blocks x 32 cols)

#if __has_builtin(__builtin_amdgcn_exp2f)
__device__ __forceinline__ float fexp2(float x) { return __builtin_amdgcn_exp2f(x); }
#else
__device__ __forceinline__ float fexp2(float x) { return exp2f(x); }
#endif
#if __has_builtin(__builtin_amdgcn_logf)
__device__ __forceinline__ float flog2(float x) { return __builtin_amdgcn_logf(x); }
#else
__device__ __forceinline__ float flog2(float x) { return __log2f(x); }
#endif
#if __has_builtin(__builtin_amdgcn_rcpf)
__device__ __forceinline__ float frcp(float x) { return __builtin_amdgcn_rcpf(x); }
#else
__device__ __forceinline__ float frcp(float x) { return 1.0f / x; }
#endif

// ---------------- Kernel A: per-block partial column minima ----------------
__global__ __launch_bounds__(256) void k_min(const float* __restrict__ phi,
                                             float* __restrict__ ws) {
    __shared__ float sm[1024];
    const int tid = threadIdx.x;
    const int g = blockIdx.x * 256 + tid;
    const float4* __restrict__ p4 = (const float4*)phi;
    float4 m = p4[g];
    #pragma unroll
    for (int k = 1; k < 16; ++k) {
        float4 v = p4[g + k * 65536];
        m.x = fminf(m.x, v.x); m.y = fminf(m.y, v.y);
        m.z = fminf(m.z, v.z); m.w = fminf(m.w, v.w);
    }
    sm[tid * 4 + 0] = m.x; sm[tid * 4 + 1] = m.y;
    sm[tid * 4 + 2] = m.z; sm[tid * 4 + 3] = m.w;
    __syncthreads();
    #pragma unroll
    for (int s = 128; s >= 8; s >>= 1) {
        if (tid < s) {
            sm[tid * 4 + 0] = fminf(sm[tid * 4 + 0], sm[(tid + s) * 4 + 0]);
            sm[tid * 4 + 1] = fminf(sm[tid * 4 + 1], sm[(tid + s) * 4 + 1]);
            sm[tid * 4 + 2] = fminf(sm[tid * 4 + 2], sm[(tid + s) * 4 + 2]);
            sm[tid * 4 + 3] = fminf(sm[tid * 4 + 3], sm[(tid + s) * 4 + 3]);
        }
        __syncthreads();
    }
    if (tid < 8) {
        #pragma unroll
        for (int s2 = 0; s2 < 4; ++s2)
            ws[2048 + blockIdx.x * 32 + tid * 4 + s2] = sm[tid * 4 + s2];
    }
}

// ------- Kernel B: final min reduce + Gamma symmetrization into ws --------
__global__ __launch_bounds__(256) void k_prep(const float* __restrict__ Gamma,
                                              float* __restrict__ ws) {
    __shared__ float sm[256];
    const int tid = threadIdx.x;
    const int c = tid & 31, h = tid >> 5;      // 8 groups of 32 partial-blocks
    float m = INFINITY;
    #pragma unroll
    for (int b = 0; b < 32; ++b)
        m = fminf(m, ws[2048 + (h * 32 + b) * 32 + c]);
    sm[tid] = m;
    __syncthreads();
    if (tid < 32) {
        float mm = sm[tid];
        #pragma unroll
        for (int g2 = 1; g2 < 8; ++g2) mm = fminf(mm, sm[g2 * 32 + tid]);
        ws[1024 + tid] = mm - EC;
    }
    // Gsym[i][j] = Gamma[min(i,j), max(i,j)]
    #pragma unroll
    for (int k = 0; k < 4; ++k) {
        int idx = tid + 256 * k;
        int i = idx >> 5, j = idx & 31;
        int lo = min(i, j), hi = i + j - lo;
        ws[idx] = Gamma[lo * 32 + hi];
    }
}

// ---------------- Kernel C: main (row-per-thread) --------------------------
// 512 blocks x 256 threads, one row per thread. FULLY UNROLLED: every array
// index is compile-time-constant, so L[32]/acc[32]/xs[32] live purely in
// registers — no LDS mirror, no dynamic indexing (scratch demotion cannot
// trigger), no ds_read latency on the critical path. Pairwise symmetric form
// (Gsym[i][j]==Gsym[j][i]): term(i,j)=2^(Lj+g*d), term(j,i)=2^(Li-g*d) with
// d=Li-Lj shared -> 496 pairs x {1 sub, 2 fma, 2 exp2, 2 add} instead of
// 1024 x {1 sub, 1 fma, 1 exp2, 1 add}. g's are wave-uniform s_loads with
// compile-time offsets. P[i]=phic_i kept from the load phase so the diagonal
// term needs no exp2(log2(x)) round-trip.
__global__ __launch_bounds__(256, 2) void k_main(const float* __restrict__ phi,
                                                 const float* __restrict__ w,
                                                 const float* __restrict__ ws,
                                                 float* __restrict__ out) {
    const int tid = threadIdx.x;
    const size_t row = (size_t)blockIdx.x * 256 + tid;
    const float* __restrict__ pr = phi + row * NM;
    const float* __restrict__ mme = ws + 1024;   // mode_min - e (uniform)

    float L[32];
    float acc[32];
    // load + clamp + log2; seed acc with the diagonal term (1+w_i)*phic_i
    #pragma unroll
    for (int k = 0; k < 8; ++k) {
        float4 v = ((const float4*)pr)[k];
        // phic = max(phi - mode_min + e, e) = max(phi - (mode_min - e), e)
        float p0 = fmaxf(v.x - mme[4 * k + 0], EC);
        float p1 = fmaxf(v.y - mme[4 * k + 1], EC);
        float p2 = fmaxf(v.z - mme[4 * k + 2], EC);
        float p3 = fmaxf(v.w - mme[4 * k + 3], EC);
        L[4 * k + 0] = flog2(p0); L[4 * k + 1] = flog2(p1);
        L[4 * k + 2] = flog2(p2); L[4 * k + 3] = flog2(p3);
        // (1+w)*p = fmaf(w, p, p)
        acc[4 * k + 0] = fmaf(w[4 * k + 0], p0, p0);
        acc[4 * k + 1] = fmaf(w[4 * k + 1], p1, p1);
        acc[4 * k + 2] = fmaf(w[4 * k + 2], p2, p2);
        acc[4 * k + 3] = fmaf(w[4 * k + 3], p3, p3);
    }

    // upper-triangle pairs, all indices static
    #pragma unroll
    for (int i = 0; i < 31; ++i) {
        #pragma unroll
        for (int j = i + 1; j < 32; ++j) {
            const float g = ws[i * 32 + j];      // uniform s_load, imm offset
            const float d = L[i] - L[j];
            acc[i] += fexp2(fmaf(g, d, L[j]));   // phic_i^g * phic_j^(1-g)
            acc[j] += fexp2(fmaf(g, -d, L[i]));  // phic_j^g * phic_i^(1-g)
        }
    }

    float xs[32];
    #pragma unroll
    for (int i = 0; i < 32; ++i) xs[i] = -TS * acc[i];
    float m = xs[0];
    #pragma unroll
    for (int i = 1; i < 32; ++i) m = fmaxf(m, xs[i]);
    float p[32];
    float s = 0.f;
    #pragma unroll
    for (int i = 0; i < 32; ++i) { p[i] = fexp2((xs[i] - m) * L2E); s += p[i]; }
    const float inv = frcp(s);
    const float lns = flog2(s) * LN2F;   // ln(s)

    float* __restrict__ oa = out + row * NM;
    float* __restrict__ ol = out + (size_t)NB * NM + row * NM;
    #pragma unroll
    for (int k = 0; k < 8; ++k) {
        float4 a4 = { p[4 * k + 0] * inv, p[4 * k + 1] * inv,
                      p[4 * k + 2] * inv, p[4 * k + 3] * inv };
        float4 l4 = { (xs[4 * k + 0] - m) - lns, (xs[4 * k + 1] - m) - lns,
                      (xs[4 * k + 2] - m) - lns, (xs[4 * k + 3] - m) - lns };
        ((float4*)oa)[k] = a4;
        ((float4*)ol)[k] = l4;
    }
}

extern "C" void kernel_launch(void* const* d_in, const int* in_sizes, int n_in,
                              void* d_out, int out_size, void* d_ws, size_t ws_size,
                              hipStream_t stream) {
    (void)in_sizes; (void)n_in; (void)out_size; (void)ws_size;
    const float* phi   = (const float*)d_in[0];
    const float* Gamma = (const float*)d_in[1];
    const float* w     = (const float*)d_in[2];
    float* out = (float*)d_out;
    float* wsf = (float*)d_ws;

    k_min<<<256, 256, 0, stream>>>(phi, wsf);
    k_prep<<<1, 256, 0, stream>>>(Gamma, wsf);
    k_main<<<512, 256, 0, stream>>>(phi, w, wsf, out);
}